// Round 4
// baseline (1488.430 us; speedup 1.0000x reference)
//
#include <hip/hip_runtime.h>
#include <math.h>

#define TCTX 4096
#define HEADS 16
#define W3 3072
#define BQ 64
#define BK 64
#define LSTR 65   // float LDS row stride (proven R1/R6 layout)
#define HSTR 72   // short LDS row stride (144B rows, 16B aligned)

typedef short bf16x8 __attribute__((ext_vector_type(8)));
typedef float f32x4 __attribute__((ext_vector_type(4)));

static __device__ __forceinline__ unsigned short f2bf(float x) {
    union { float f; unsigned int u; } v; v.f = x;
    unsigned int r = v.u + 0x7fffu + ((v.u >> 16) & 1u);  // RNE
    return (unsigned short)(r >> 16);
}
static __device__ __forceinline__ float bf2f(unsigned short h) {
    union { float f; unsigned int u; } v; v.u = ((unsigned int)h) << 16;
    return v.f;
}
#define PK2(a,b) ((unsigned int)(a) | ((unsigned int)(b) << 16))

// R11 = R7 byte-identical control re-run. R7 is the only harness-verified
// artifact (1482.7us, passed). R8 (aliasing) corrupted; R9/R10 (reduction
// reorders) landed at 2.57e-3/2.93e-3 vs threshold 2.5195e-3. This run
// re-anchors: measures R7's margin under TODAY's harness and finally
// produces rocprof counters for the performance theory.
__global__ __launch_bounds__(256, 1) void attn_r7_kernel(
    const float* __restrict__ qkv,
    const float* __restrict__ q_gamma, const float* __restrict__ q_beta,
    const float* __restrict__ k_gamma, const float* __restrict__ k_beta,
    float* __restrict__ out)
{
    __shared__ float Qs[BQ * LSTR];
    __shared__ float Ks[BK * LSTR];
    __shared__ float Ss[BQ * LSTR];          // S scatter (fp32)
    __shared__ unsigned short Qh[BQ * HSTR], Ql[BQ * HSTR];
    __shared__ unsigned short Kh[BK * HSTR], Kl[BK * HSTR];
    __shared__ unsigned short Vth[64 * HSTR], Vtl[64 * HSTR];  // [ch][key]
    __shared__ unsigned short Ph[BQ * HSTR], Pl[BQ * HSTR];    // [row][key]
    __shared__ float axs[BQ];   // per-row alpha (thread layout -> C layout)
    __shared__ float lin[BQ];   // per-row 1/l

    const int tid  = threadIdx.x;
    const int h    = blockIdx.y;
    const int q0   = blockIdx.x * BQ;
    const int lane = tid & 63;
    const int wv   = tid >> 6;
    const int l15  = lane & 15;
    const int quad = lane >> 4;
    const int m0   = wv * 16;
    const int r    = tid >> 2;
    const int j    = tid & 3;

    const float scale = 0.35355339059327373f;  // 64^(-1/4)

    // ---- stage Q tile (R6 verbatim) ----
    for (int i = 0; i < 16; ++i) {
        int idx = tid + i * 256;
        int rr = idx >> 6, cc = idx & 63;
        Qs[rr * LSTR + cc] = qkv[(size_t)(q0 + rr) * W3 + h * 192 + cc];
    }
    __syncthreads();

    // ---- LayerNorm Q rows + hi/lo emit (R6, dead Qs write-back dropped) ----
    {
        float s = 0.f, s2 = 0.f;
        for (int i = 0; i < 16; ++i) {
            float x = Qs[r * LSTR + j * 16 + i];
            s += x; s2 += x * x;
        }
        s  += __shfl_xor(s, 1);  s  += __shfl_xor(s, 2);
        s2 += __shfl_xor(s2, 1); s2 += __shfl_xor(s2, 2);
        float mu   = s * (1.f / 64.f);
        float var  = s2 * (1.f / 64.f) - mu * mu;
        float rsig = rsqrtf(var + 1e-6f);
        unsigned short hi[16], lo[16];
        for (int i = 0; i < 16; ++i) {
            int c = j * 16 + i;
            float x = Qs[r * LSTR + c];
            float y = ((x - mu) * rsig * q_gamma[c] + q_beta[c]) * scale;
            unsigned short yh = f2bf(y);
            hi[i] = yh;
            lo[i] = f2bf(y - bf2f(yh));
        }
        uint4* dh = (uint4*)(Qh + r * HSTR + j * 16);
        dh[0] = make_uint4(PK2(hi[0],hi[1]), PK2(hi[2],hi[3]), PK2(hi[4],hi[5]), PK2(hi[6],hi[7]));
        dh[1] = make_uint4(PK2(hi[8],hi[9]), PK2(hi[10],hi[11]), PK2(hi[12],hi[13]), PK2(hi[14],hi[15]));
        uint4* dl = (uint4*)(Ql + r * HSTR + j * 16);
        dl[0] = make_uint4(PK2(lo[0],lo[1]), PK2(lo[2],lo[3]), PK2(lo[4],lo[5]), PK2(lo[6],lo[7]));
        dl[1] = make_uint4(PK2(lo[8],lo[9]), PK2(lo[10],lo[11]), PK2(lo[12],lo[13]), PK2(lo[14],lo[15]));
    }
    __syncthreads();

    // hoist Q fragments (A[m=lane&15][k=quad*8+j]) — Qh/Ql LDS dead afterwards
    bf16x8 qh0 = *(const bf16x8*)(Qh + (m0 + l15) * HSTR +      quad * 8);
    bf16x8 qh1 = *(const bf16x8*)(Qh + (m0 + l15) * HSTR + 32 + quad * 8);
    bf16x8 ql0 = *(const bf16x8*)(Ql + (m0 + l15) * HSTR +      quad * 8);
    bf16x8 ql1 = *(const bf16x8*)(Ql + (m0 + l15) * HSTR + 32 + quad * 8);

    // softmax state per thread (r,j); O accumulator in MFMA C-layout per lane
    float m = -1e30f;
    float l = 0.f;
    f32x4 acco[4];
    #pragma unroll
    for (int t = 0; t < 4; ++t) acco[t] = (f32x4){0.f, 0.f, 0.f, 0.f};

    for (int s0 = 0; s0 < TCTX; s0 += BK) {
        __syncthreads();  // prior tile's Kh/Kl/Vth/Vtl/Ph/Pl/Ss reads complete

        // ---- stage K -> Ks fp32 (R6 loader, K only) ----
        for (int i = 0; i < 16; ++i) {
            int idx = tid + i * 256;
            int rr = idx >> 6, cc = idx & 63;
            Ks[rr * LSTR + cc] = qkv[(size_t)(s0 + rr) * W3 + h * 192 + 64 + cc];
        }
        // ---- stage V transposed hi/lo: Vth/Vtl[ch][key] ----
        {
            const float4* src = (const float4*)(qkv + (size_t)(s0 + r) * W3 + h * 192 + 128 + j * 16);
            #pragma unroll
            for (int c = 0; c < 4; ++c) {
                float4 v4 = src[c];
                float vv[4] = {v4.x, v4.y, v4.z, v4.w};
                #pragma unroll
                for (int k = 0; k < 4; ++k) {
                    unsigned short vh = f2bf(vv[k]);
                    Vth[(j*16 + 4*c + k) * HSTR + r] = vh;
                    Vtl[(j*16 + 4*c + k) * HSTR + r] = f2bf(vv[k] - bf2f(vh));
                }
            }
        }
        __syncthreads();

        // ---- LayerNorm K rows + hi/lo emit (R6, dead Ks write-back dropped) ----
        {
            float s = 0.f, s2 = 0.f;
            for (int i = 0; i < 16; ++i) {
                float x = Ks[r * LSTR + j * 16 + i];
                s += x; s2 += x * x;
            }
            s  += __shfl_xor(s, 1);  s  += __shfl_xor(s, 2);
            s2 += __shfl_xor(s2, 1); s2 += __shfl_xor(s2, 2);
            float mu   = s * (1.f / 64.f);
            float var  = s2 * (1.f / 64.f) - mu * mu;
            float rsig = rsqrtf(var + 1e-6f);
            unsigned short hi[16], lo[16];
            for (int i = 0; i < 16; ++i) {
                int c = j * 16 + i;
                float x = Ks[r * LSTR + c];
                float y = ((x - mu) * rsig * k_gamma[c] + k_beta[c]) * scale;
                unsigned short yh = f2bf(y);
                hi[i] = yh;
                lo[i] = f2bf(y - bf2f(yh));
            }
            uint4* dh = (uint4*)(Kh + r * HSTR + j * 16);
            dh[0] = make_uint4(PK2(hi[0],hi[1]), PK2(hi[2],hi[3]), PK2(hi[4],hi[5]), PK2(hi[6],hi[7]));
            dh[1] = make_uint4(PK2(hi[8],hi[9]), PK2(hi[10],hi[11]), PK2(hi[12],hi[13]), PK2(hi[14],hi[15]));
            uint4* dl = (uint4*)(Kl + r * HSTR + j * 16);
            dl[0] = make_uint4(PK2(lo[0],lo[1]), PK2(lo[2],lo[3]), PK2(lo[4],lo[5]), PK2(lo[6],lo[7]));
            dl[1] = make_uint4(PK2(lo[8],lo[9]), PK2(lo[10],lo[11]), PK2(lo[12],lo[13]), PK2(lo[14],lo[15]));
        }
        __syncthreads();

        // ---- S = Q K^T via split MFMA, scatter C-layout -> Ss fp32 (R6 verbatim) ----
        {
            f32x4 accs[4];
            #pragma unroll
            for (int t = 0; t < 4; ++t) accs[t] = (f32x4){0.f, 0.f, 0.f, 0.f};
            #pragma unroll
            for (int s = 0; s < 2; ++s) {
                bf16x8 qh = s ? qh1 : qh0;
                bf16x8 ql = s ? ql1 : ql0;
                #pragma unroll
                for (int t = 0; t < 4; ++t) {
                    bf16x8 kh = *(const bf16x8*)(Kh + (t*16 + l15) * HSTR + s*32 + quad*8);
                    bf16x8 kl = *(const bf16x8*)(Kl + (t*16 + l15) * HSTR + s*32 + quad*8);
                    accs[t] = __builtin_amdgcn_mfma_f32_16x16x32_bf16(ql, kh, accs[t], 0, 0, 0);
                    accs[t] = __builtin_amdgcn_mfma_f32_16x16x32_bf16(qh, kl, accs[t], 0, 0, 0);
                    accs[t] = __builtin_amdgcn_mfma_f32_16x16x32_bf16(qh, kh, accs[t], 0, 0, 0);
                }
            }
            #pragma unroll
            for (int t = 0; t < 4; ++t)
                #pragma unroll
                for (int i = 0; i < 4; ++i)
                    Ss[(m0 + quad*4 + i) * LSTR + t*16 + l15] = accs[t][i];
        }
        __syncthreads();

        // ---- softmax in (r,j) layout (R6 logic); NEW: emit Ph/Pl + axs ----
        {
            float sv[16];
            for (int i = 0; i < 16; ++i)
                sv[i] = Ss[r * LSTR + j * 16 + i];

            float tmax = sv[0];
            for (int i = 1; i < 16; ++i) tmax = fmaxf(tmax, sv[i]);
            tmax = fmaxf(tmax, __shfl_xor(tmax, 1));
            tmax = fmaxf(tmax, __shfl_xor(tmax, 2));
            float new_m = fmaxf(m, tmax);
            float alpha = __expf(m - new_m);
            float psum = 0.f;
            unsigned short hi[16], lo[16];
            for (int i = 0; i < 16; ++i) {
                float p = __expf(sv[i] - new_m);
                psum += p;
                unsigned short ph = f2bf(p);
                hi[i] = ph;
                lo[i] = f2bf(p - bf2f(ph));
            }
            psum += __shfl_xor(psum, 1);
            psum += __shfl_xor(psum, 2);
            l = l * alpha + psum;
            m = new_m;
            uint4* dh = (uint4*)(Ph + r * HSTR + j * 16);
            dh[0] = make_uint4(PK2(hi[0],hi[1]), PK2(hi[2],hi[3]), PK2(hi[4],hi[5]), PK2(hi[6],hi[7]));
            dh[1] = make_uint4(PK2(hi[8],hi[9]), PK2(hi[10],hi[11]), PK2(hi[12],hi[13]), PK2(hi[14],hi[15]));
            uint4* dl = (uint4*)(Pl + r * HSTR + j * 16);
            dl[0] = make_uint4(PK2(lo[0],lo[1]), PK2(lo[2],lo[3]), PK2(lo[4],lo[5]), PK2(lo[6],lo[7]));
            dl[1] = make_uint4(PK2(lo[8],lo[9]), PK2(lo[10],lo[11]), PK2(lo[12],lo[13]), PK2(lo[14],lo[15]));
            if (j == 0) axs[r] = alpha;
        }
        __syncthreads();  // Ph/Pl + axs visible

        // ---- rescale O (C-layout rows m0+quad*4+i) ----
        {
            float af[4];
            #pragma unroll
            for (int i = 0; i < 4; ++i) af[i] = axs[m0 + quad*4 + i];
            #pragma unroll
            for (int t = 0; t < 4; ++t)
                #pragma unroll
                for (int i = 0; i < 4; ++i)
                    acco[t][i] *= af[i];
        }

        // ---- O += P V via split MFMA (A path ≡ proven Q path, B ≡ proven K path) ----
        #pragma unroll
        for (int s = 0; s < 2; ++s) {
            bf16x8 pa_h = *(const bf16x8*)(Ph + (m0 + l15) * HSTR + s*32 + quad*8);
            bf16x8 pa_l = *(const bf16x8*)(Pl + (m0 + l15) * HSTR + s*32 + quad*8);
            #pragma unroll
            for (int t = 0; t < 4; ++t) {
                bf16x8 vb_h = *(const bf16x8*)(Vth + (t*16 + l15) * HSTR + s*32 + quad*8);
                bf16x8 vb_l = *(const bf16x8*)(Vtl + (t*16 + l15) * HSTR + s*32 + quad*8);
                acco[t] = __builtin_amdgcn_mfma_f32_16x16x32_bf16(pa_l, vb_h, acco[t], 0, 0, 0);
                acco[t] = __builtin_amdgcn_mfma_f32_16x16x32_bf16(pa_h, vb_l, acco[t], 0, 0, 0);
                acco[t] = __builtin_amdgcn_mfma_f32_16x16x32_bf16(pa_h, vb_h, acco[t], 0, 0, 0);
            }
        }
    }

    // ---- epilogue: 1/l broadcast, normalize, C-layout store (proven mapping) ----
    if (j == 0) lin[r] = 1.f / l;
    __syncthreads();
    {
        float il[4];
        #pragma unroll
        for (int i = 0; i < 4; ++i) il[i] = lin[m0 + quad*4 + i];
        #pragma unroll
        for (int i = 0; i < 4; ++i) {
            const int row = q0 + m0 + quad*4 + i;
            float* op = out + (size_t)row * (HEADS * 64) + h * 64 + l15;
            #pragma unroll
            for (int t = 0; t < 4; ++t)
                op[t * 16] = acco[t][i] * il[i];
        }
    }
}

extern "C" void kernel_launch(void* const* d_in, const int* in_sizes, int n_in,
                              void* d_out, int out_size, void* d_ws, size_t ws_size,
                              hipStream_t stream) {
    const float* qkv     = (const float*)d_in[0];
    const float* q_gamma = (const float*)d_in[1];
    const float* q_beta  = (const float*)d_in[2];
    const float* k_gamma = (const float*)d_in[3];
    const float* k_beta  = (const float*)d_in[4];
    float* out = (float*)d_out;

    dim3 grid(TCTX / BQ, HEADS);
    attn_r7_kernel<<<grid, 256, 0, stream>>>(qkv, q_gamma, q_beta,
                                             k_gamma, k_beta, out);
}

// Round 5
// 1378.300 us; speedup vs baseline: 1.0799x; 1.0799x over previous
//
#include <hip/hip_runtime.h>
#include <math.h>

#define TCTX 4096
#define HEADS 16
#define W3 3072
#define BQ 64
#define BK 64
#define LSTR 65   // float LDS row stride (proven R1/R6 layout)
#define HSTR 72   // short LDS row stride (144B rows, 16B aligned)

typedef short bf16x8 __attribute__((ext_vector_type(8)));
typedef float f32x4 __attribute__((ext_vector_type(4)));

static __device__ __forceinline__ unsigned short f2bf(float x) {
    union { float f; unsigned int u; } v; v.f = x;
    unsigned int r = v.u + 0x7fffu + ((v.u >> 16) & 1u);  // RNE
    return (unsigned short)(r >> 16);
}
static __device__ __forceinline__ float bf2f(unsigned short h) {
    union { float f; unsigned int u; } v; v.u = ((unsigned int)h) << 16;
    return v.f;
}
#define PK2(a,b) ((unsigned int)(a) | ((unsigned int)(b) << 16))

// R12 = R7 (verified: passed, absmax 4.88e-4, 1488us) with ONE provably
// value-identical change: Qs/Ks fp32 LDS staging replaced by direct
// global->register loads in the SAME (r,j) thread mapping with the SAME
// serial LN summation order. Thread (r,j) previously read
// Qs/Ks[r*LSTR + j*16 + i] == qkv[(row)*W3 + h*192 (+64) + j*16 + i];
// it now loads those exact floats itself. Deletes 2 LDS buffers (33KB),
// the staging loops, and 2 barriers (1 prologue + barrier B).
// Everything else (QK^T, scatter, softmax, PV, epilogue) is R7-verbatim.
__global__ __launch_bounds__(256, 1) void attn_r12_kernel(
    const float* __restrict__ qkv,
    const float* __restrict__ q_gamma, const float* __restrict__ q_beta,
    const float* __restrict__ k_gamma, const float* __restrict__ k_beta,
    float* __restrict__ out)
{
    __shared__ float Ss[BQ * LSTR];          // S scatter (fp32)
    __shared__ unsigned short Qh[BQ * HSTR], Ql[BQ * HSTR];
    __shared__ unsigned short Kh[BK * HSTR], Kl[BK * HSTR];
    __shared__ unsigned short Vth[64 * HSTR], Vtl[64 * HSTR];  // [ch][key]
    __shared__ unsigned short Ph[BQ * HSTR], Pl[BQ * HSTR];    // [row][key]
    __shared__ float axs[BQ];   // per-row alpha (thread layout -> C layout)
    __shared__ float lin[BQ];   // per-row 1/l

    const int tid  = threadIdx.x;
    const int h    = blockIdx.y;
    const int q0   = blockIdx.x * BQ;
    const int lane = tid & 63;
    const int wv   = tid >> 6;
    const int l15  = lane & 15;
    const int quad = lane >> 4;
    const int m0   = wv * 16;
    const int r    = tid >> 2;
    const int j    = tid & 3;

    const float scale = 0.35355339059327373f;  // 64^(-1/4)

    // ---- LayerNorm Q: direct global->reg load, R7-identical math order ----
    {
        const float* qp = qkv + (size_t)(q0 + r) * W3 + h * 192 + j * 16;
        f32x4 x0 = *(const f32x4*)(qp);
        f32x4 x1 = *(const f32x4*)(qp + 4);
        f32x4 x2 = *(const f32x4*)(qp + 8);
        f32x4 x3 = *(const f32x4*)(qp + 12);
        float s = 0.f, s2 = 0.f;
        #pragma unroll
        for (int i = 0; i < 16; ++i) {
            float x = (i < 4 ? x0[i & 3] : i < 8 ? x1[i & 3] : i < 12 ? x2[i & 3] : x3[i & 3]);
            s += x; s2 += x * x;
        }
        s  += __shfl_xor(s, 1);  s  += __shfl_xor(s, 2);
        s2 += __shfl_xor(s2, 1); s2 += __shfl_xor(s2, 2);
        float mu   = s * (1.f / 64.f);
        float var  = s2 * (1.f / 64.f) - mu * mu;
        float rsig = rsqrtf(var + 1e-6f);
        unsigned short hi[16], lo[16];
        #pragma unroll
        for (int i = 0; i < 16; ++i) {
            int c = j * 16 + i;
            float x = (i < 4 ? x0[i & 3] : i < 8 ? x1[i & 3] : i < 12 ? x2[i & 3] : x3[i & 3]);
            float y = ((x - mu) * rsig * q_gamma[c] + q_beta[c]) * scale;
            unsigned short yh = f2bf(y);
            hi[i] = yh;
            lo[i] = f2bf(y - bf2f(yh));
        }
        uint4* dh = (uint4*)(Qh + r * HSTR + j * 16);
        dh[0] = make_uint4(PK2(hi[0],hi[1]), PK2(hi[2],hi[3]), PK2(hi[4],hi[5]), PK2(hi[6],hi[7]));
        dh[1] = make_uint4(PK2(hi[8],hi[9]), PK2(hi[10],hi[11]), PK2(hi[12],hi[13]), PK2(hi[14],hi[15]));
        uint4* dl = (uint4*)(Ql + r * HSTR + j * 16);
        dl[0] = make_uint4(PK2(lo[0],lo[1]), PK2(lo[2],lo[3]), PK2(lo[4],lo[5]), PK2(lo[6],lo[7]));
        dl[1] = make_uint4(PK2(lo[8],lo[9]), PK2(lo[10],lo[11]), PK2(lo[12],lo[13]), PK2(lo[14],lo[15]));
    }
    __syncthreads();

    // hoist Q fragments (A[m=lane&15][k=quad*8+j]) — Qh/Ql LDS dead afterwards
    bf16x8 qh0 = *(const bf16x8*)(Qh + (m0 + l15) * HSTR +      quad * 8);
    bf16x8 qh1 = *(const bf16x8*)(Qh + (m0 + l15) * HSTR + 32 + quad * 8);
    bf16x8 ql0 = *(const bf16x8*)(Ql + (m0 + l15) * HSTR +      quad * 8);
    bf16x8 ql1 = *(const bf16x8*)(Ql + (m0 + l15) * HSTR + 32 + quad * 8);

    // softmax state per thread (r,j); O accumulator in MFMA C-layout per lane
    float m = -1e30f;
    float l = 0.f;
    f32x4 acco[4];
    #pragma unroll
    for (int t = 0; t < 4; ++t) acco[t] = (f32x4){0.f, 0.f, 0.f, 0.f};

    for (int s0 = 0; s0 < TCTX; s0 += BK) {
        __syncthreads();  // A: prior tile's Kh/Kl/Vth/Vtl/Ph/Pl/Ss reads complete

        // ---- K: direct global->reg load (issued first to overlap V staging) ----
        const float* kp = qkv + (size_t)(s0 + r) * W3 + h * 192 + 64 + j * 16;
        f32x4 k0 = *(const f32x4*)(kp);
        f32x4 k1 = *(const f32x4*)(kp + 4);
        f32x4 k2 = *(const f32x4*)(kp + 8);
        f32x4 k3 = *(const f32x4*)(kp + 12);

        // ---- stage V transposed hi/lo: Vth/Vtl[ch][key] (R7 verbatim) ----
        {
            const float4* src = (const float4*)(qkv + (size_t)(s0 + r) * W3 + h * 192 + 128 + j * 16);
            #pragma unroll
            for (int c = 0; c < 4; ++c) {
                float4 v4 = src[c];
                float vv[4] = {v4.x, v4.y, v4.z, v4.w};
                #pragma unroll
                for (int k = 0; k < 4; ++k) {
                    unsigned short vh = f2bf(vv[k]);
                    Vth[(j*16 + 4*c + k) * HSTR + r] = vh;
                    Vtl[(j*16 + 4*c + k) * HSTR + r] = f2bf(vv[k] - bf2f(vh));
                }
            }
        }

        // ---- LayerNorm K on registers (R7-identical order) + hi/lo emit ----
        {
            float s = 0.f, s2 = 0.f;
            #pragma unroll
            for (int i = 0; i < 16; ++i) {
                float x = (i < 4 ? k0[i & 3] : i < 8 ? k1[i & 3] : i < 12 ? k2[i & 3] : k3[i & 3]);
                s += x; s2 += x * x;
            }
            s  += __shfl_xor(s, 1);  s  += __shfl_xor(s, 2);
            s2 += __shfl_xor(s2, 1); s2 += __shfl_xor(s2, 2);
            float mu   = s * (1.f / 64.f);
            float var  = s2 * (1.f / 64.f) - mu * mu;
            float rsig = rsqrtf(var + 1e-6f);
            unsigned short hi[16], lo[16];
            #pragma unroll
            for (int i = 0; i < 16; ++i) {
                int c = j * 16 + i;
                float x = (i < 4 ? k0[i & 3] : i < 8 ? k1[i & 3] : i < 12 ? k2[i & 3] : k3[i & 3]);
                float y = ((x - mu) * rsig * k_gamma[c] + k_beta[c]) * scale;
                unsigned short yh = f2bf(y);
                hi[i] = yh;
                lo[i] = f2bf(y - bf2f(yh));
            }
            uint4* dh = (uint4*)(Kh + r * HSTR + j * 16);
            dh[0] = make_uint4(PK2(hi[0],hi[1]), PK2(hi[2],hi[3]), PK2(hi[4],hi[5]), PK2(hi[6],hi[7]));
            dh[1] = make_uint4(PK2(hi[8],hi[9]), PK2(hi[10],hi[11]), PK2(hi[12],hi[13]), PK2(hi[14],hi[15]));
            uint4* dl = (uint4*)(Kl + r * HSTR + j * 16);
            dl[0] = make_uint4(PK2(lo[0],lo[1]), PK2(lo[2],lo[3]), PK2(lo[4],lo[5]), PK2(lo[6],lo[7]));
            dl[1] = make_uint4(PK2(lo[8],lo[9]), PK2(lo[10],lo[11]), PK2(lo[12],lo[13]), PK2(lo[14],lo[15]));
        }
        __syncthreads();  // C: Kh/Kl + Vth/Vtl visible

        // ---- S = Q K^T via split MFMA, scatter C-layout -> Ss fp32 (R7 verbatim) ----
        {
            f32x4 accs[4];
            #pragma unroll
            for (int t = 0; t < 4; ++t) accs[t] = (f32x4){0.f, 0.f, 0.f, 0.f};
            #pragma unroll
            for (int s = 0; s < 2; ++s) {
                bf16x8 qh = s ? qh1 : qh0;
                bf16x8 ql = s ? ql1 : ql0;
                #pragma unroll
                for (int t = 0; t < 4; ++t) {
                    bf16x8 kh = *(const bf16x8*)(Kh + (t*16 + l15) * HSTR + s*32 + quad*8);
                    bf16x8 kl = *(const bf16x8*)(Kl + (t*16 + l15) * HSTR + s*32 + quad*8);
                    accs[t] = __builtin_amdgcn_mfma_f32_16x16x32_bf16(ql, kh, accs[t], 0, 0, 0);
                    accs[t] = __builtin_amdgcn_mfma_f32_16x16x32_bf16(qh, kl, accs[t], 0, 0, 0);
                    accs[t] = __builtin_amdgcn_mfma_f32_16x16x32_bf16(qh, kh, accs[t], 0, 0, 0);
                }
            }
            #pragma unroll
            for (int t = 0; t < 4; ++t)
                #pragma unroll
                for (int i = 0; i < 4; ++i)
                    Ss[(m0 + quad*4 + i) * LSTR + t*16 + l15] = accs[t][i];
        }
        __syncthreads();  // D: Ss visible

        // ---- softmax in (r,j) layout (R7 verbatim) ----
        {
            float sv[16];
            for (int i = 0; i < 16; ++i)
                sv[i] = Ss[r * LSTR + j * 16 + i];

            float tmax = sv[0];
            for (int i = 1; i < 16; ++i) tmax = fmaxf(tmax, sv[i]);
            tmax = fmaxf(tmax, __shfl_xor(tmax, 1));
            tmax = fmaxf(tmax, __shfl_xor(tmax, 2));
            float new_m = fmaxf(m, tmax);
            float alpha = __expf(m - new_m);
            float psum = 0.f;
            unsigned short hi[16], lo[16];
            for (int i = 0; i < 16; ++i) {
                float p = __expf(sv[i] - new_m);
                psum += p;
                unsigned short ph = f2bf(p);
                hi[i] = ph;
                lo[i] = f2bf(p - bf2f(ph));
            }
            psum += __shfl_xor(psum, 1);
            psum += __shfl_xor(psum, 2);
            l = l * alpha + psum;
            m = new_m;
            uint4* dh = (uint4*)(Ph + r * HSTR + j * 16);
            dh[0] = make_uint4(PK2(hi[0],hi[1]), PK2(hi[2],hi[3]), PK2(hi[4],hi[5]), PK2(hi[6],hi[7]));
            dh[1] = make_uint4(PK2(hi[8],hi[9]), PK2(hi[10],hi[11]), PK2(hi[12],hi[13]), PK2(hi[14],hi[15]));
            uint4* dl = (uint4*)(Pl + r * HSTR + j * 16);
            dl[0] = make_uint4(PK2(lo[0],lo[1]), PK2(lo[2],lo[3]), PK2(lo[4],lo[5]), PK2(lo[6],lo[7]));
            dl[1] = make_uint4(PK2(lo[8],lo[9]), PK2(lo[10],lo[11]), PK2(lo[12],lo[13]), PK2(lo[14],lo[15]));
            if (j == 0) axs[r] = alpha;
        }
        __syncthreads();  // E: Ph/Pl + axs visible

        // ---- rescale O (C-layout rows m0+quad*4+i) ----
        {
            float af[4];
            #pragma unroll
            for (int i = 0; i < 4; ++i) af[i] = axs[m0 + quad*4 + i];
            #pragma unroll
            for (int t = 0; t < 4; ++t)
                #pragma unroll
                for (int i = 0; i < 4; ++i)
                    acco[t][i] *= af[i];
        }

        // ---- O += P V via split MFMA (R7 verbatim) ----
        #pragma unroll
        for (int s = 0; s < 2; ++s) {
            bf16x8 pa_h = *(const bf16x8*)(Ph + (m0 + l15) * HSTR + s*32 + quad*8);
            bf16x8 pa_l = *(const bf16x8*)(Pl + (m0 + l15) * HSTR + s*32 + quad*8);
            #pragma unroll
            for (int t = 0; t < 4; ++t) {
                bf16x8 vb_h = *(const bf16x8*)(Vth + (t*16 + l15) * HSTR + s*32 + quad*8);
                bf16x8 vb_l = *(const bf16x8*)(Vtl + (t*16 + l15) * HSTR + s*32 + quad*8);
                acco[t] = __builtin_amdgcn_mfma_f32_16x16x32_bf16(pa_l, vb_h, acco[t], 0, 0, 0);
                acco[t] = __builtin_amdgcn_mfma_f32_16x16x32_bf16(pa_h, vb_l, acco[t], 0, 0, 0);
                acco[t] = __builtin_amdgcn_mfma_f32_16x16x32_bf16(pa_h, vb_h, acco[t], 0, 0, 0);
            }
        }
    }

    // ---- epilogue: 1/l broadcast, normalize, C-layout store (R7 verbatim) ----
    if (j == 0) lin[r] = 1.f / l;
    __syncthreads();
    {
        float il[4];
        #pragma unroll
        for (int i = 0; i < 4; ++i) il[i] = lin[m0 + quad*4 + i];
        #pragma unroll
        for (int i = 0; i < 4; ++i) {
            const int row = q0 + m0 + quad*4 + i;
            float* op = out + (size_t)row * (HEADS * 64) + h * 64 + l15;
            #pragma unroll
            for (int t = 0; t < 4; ++t)
                op[t * 16] = acco[t][i] * il[i];
        }
    }
}

extern "C" void kernel_launch(void* const* d_in, const int* in_sizes, int n_in,
                              void* d_out, int out_size, void* d_ws, size_t ws_size,
                              hipStream_t stream) {
    const float* qkv     = (const float*)d_in[0];
    const float* q_gamma = (const float*)d_in[1];
    const float* q_beta  = (const float*)d_in[2];
    const float* k_gamma = (const float*)d_in[3];
    const float* k_beta  = (const float*)d_in[4];
    float* out = (float*)d_out;

    dim3 grid(TCTX / BQ, HEADS);
    attn_r12_kernel<<<grid, 256, 0, stream>>>(qkv, q_gamma, q_beta,
                                              k_gamma, k_beta, out);
}

// Round 9
// 606.204 us; speedup vs baseline: 2.4553x; 2.2737x over previous
//
#include <hip/hip_runtime.h>
#include <math.h>

#define TCTX 4096
#define HEADS 16
#define W3 3072
#define BQ 128   // NEW: 128 query rows per block (8 waves)
#define BK 64
#define NT 512
#define LSTR 65   // float LDS row stride (proven layout)
#define HSTR 72   // short LDS row stride (144B rows, 16B aligned)

typedef short bf16x8 __attribute__((ext_vector_type(8)));
typedef float f32x4 __attribute__((ext_vector_type(4)));

static __device__ __forceinline__ unsigned short f2bf(float x) {
    union { float f; unsigned int u; } v; v.f = x;
    unsigned int r = v.u + 0x7fffu + ((v.u >> 16) & 1u);  // RNE
    return (unsigned short)(r >> 16);
}
static __device__ __forceinline__ float bf2f(unsigned short h) {
    union { float f; unsigned int u; } v; v.u = ((unsigned int)h) << 16;
    return v.f;
}
#define PK2(a,b) ((unsigned int)(a) | ((unsigned int)(b) << 16))

// R16: session law discovered — every kernel whose LDS permits >=2 resident
// blocks/CU corrupts (timing-dependent, 5.6e-3..1e-2); every 1-block/CU
// kernel passes (4.88e-4). R15 (attribute-only change) proved it's resource
// co-residency, not launch_bounds. So: get wave-parallelism INSIDE one block.
// R16 = R12 per-row math VERBATIM, scaled to 512 threads / BQ=128 / 8 waves:
//   - LDS 144896 B (>81920) => co-residency structurally impossible (safe regime)
//   - 2 waves/SIMD (was 1) => latency hiding between barriers
//   - waves 0-3 do K load+LN CONCURRENT with waves 4-7 V staging (was serial)
//   - each K/V tile serves 128 rows => K/V fetch + LN work per row halved
// Per-row values bitwise identical to R12 (same thread-local math, same
// summation orders, same layouts; only writer-thread assignment and block
// geometry change).
__global__ __launch_bounds__(NT, 1) void attn_r16_kernel(
    const float* __restrict__ qkv,
    const float* __restrict__ q_gamma, const float* __restrict__ q_beta,
    const float* __restrict__ k_gamma, const float* __restrict__ k_beta,
    float* __restrict__ out)
{
    __shared__ float Ss[BQ * LSTR];                              // 33280 B
    __shared__ unsigned short Qh[BQ * HSTR], Ql[BQ * HSTR];      // 36864 B
    __shared__ unsigned short Kh[BK * HSTR], Kl[BK * HSTR];      // 18432 B
    __shared__ unsigned short Vth[64 * HSTR], Vtl[64 * HSTR];    // 18432 B [ch][key]
    __shared__ unsigned short Ph[BQ * HSTR], Pl[BQ * HSTR];      // 36864 B [row][key]
    __shared__ float axs[BQ];   // per-row alpha
    __shared__ float lin[BQ];   // per-row 1/l
    // total 144896 B -> exactly 1 block/CU on gfx950 (160 KiB LDS)

    const int tid  = threadIdx.x;
    const int h    = blockIdx.y;
    const int q0   = blockIdx.x * BQ;
    const int lane = tid & 63;
    const int wv   = tid >> 6;          // 0..7
    const int l15  = lane & 15;
    const int quad = lane >> 4;
    const int m0   = wv * 16;           // 0..112
    const int r    = tid >> 2;          // 0..127
    const int j    = tid & 3;

    const float scale = 0.35355339059327373f;  // 64^(-1/4)

    // ---- LayerNorm Q: direct global->reg load (R12 order), rows 0..127 ----
    {
        const float* qp = qkv + (size_t)(q0 + r) * W3 + h * 192 + j * 16;
        f32x4 x0 = *(const f32x4*)(qp);
        f32x4 x1 = *(const f32x4*)(qp + 4);
        f32x4 x2 = *(const f32x4*)(qp + 8);
        f32x4 x3 = *(const f32x4*)(qp + 12);
        float s = 0.f, s2 = 0.f;
        #pragma unroll
        for (int i = 0; i < 16; ++i) {
            float x = (i < 4 ? x0[i & 3] : i < 8 ? x1[i & 3] : i < 12 ? x2[i & 3] : x3[i & 3]);
            s += x; s2 += x * x;
        }
        s  += __shfl_xor(s, 1);  s  += __shfl_xor(s, 2);
        s2 += __shfl_xor(s2, 1); s2 += __shfl_xor(s2, 2);
        float mu   = s * (1.f / 64.f);
        float var  = s2 * (1.f / 64.f) - mu * mu;
        float rsig = rsqrtf(var + 1e-6f);
        unsigned short hi[16], lo[16];
        #pragma unroll
        for (int i = 0; i < 16; ++i) {
            int c = j * 16 + i;
            float x = (i < 4 ? x0[i & 3] : i < 8 ? x1[i & 3] : i < 12 ? x2[i & 3] : x3[i & 3]);
            float y = ((x - mu) * rsig * q_gamma[c] + q_beta[c]) * scale;
            unsigned short yh = f2bf(y);
            hi[i] = yh;
            lo[i] = f2bf(y - bf2f(yh));
        }
        uint4* dh = (uint4*)(Qh + r * HSTR + j * 16);
        dh[0] = make_uint4(PK2(hi[0],hi[1]), PK2(hi[2],hi[3]), PK2(hi[4],hi[5]), PK2(hi[6],hi[7]));
        dh[1] = make_uint4(PK2(hi[8],hi[9]), PK2(hi[10],hi[11]), PK2(hi[12],hi[13]), PK2(hi[14],hi[15]));
        uint4* dl = (uint4*)(Ql + r * HSTR + j * 16);
        dl[0] = make_uint4(PK2(lo[0],lo[1]), PK2(lo[2],lo[3]), PK2(lo[4],lo[5]), PK2(lo[6],lo[7]));
        dl[1] = make_uint4(PK2(lo[8],lo[9]), PK2(lo[10],lo[11]), PK2(lo[12],lo[13]), PK2(lo[14],lo[15]));
    }
    __syncthreads();

    // hoist Q fragments (A[m=lane&15][k=quad*8+j]) — Qh/Ql LDS dead afterwards
    bf16x8 qh0 = *(const bf16x8*)(Qh + (m0 + l15) * HSTR +      quad * 8);
    bf16x8 qh1 = *(const bf16x8*)(Qh + (m0 + l15) * HSTR + 32 + quad * 8);
    bf16x8 ql0 = *(const bf16x8*)(Ql + (m0 + l15) * HSTR +      quad * 8);
    bf16x8 ql1 = *(const bf16x8*)(Ql + (m0 + l15) * HSTR + 32 + quad * 8);

    // softmax state per thread (r,j); O accumulator in MFMA C-layout per lane
    float m = -1e30f;
    float l = 0.f;
    f32x4 acco[4];
    #pragma unroll
    for (int t = 0; t < 4; ++t) acco[t] = (f32x4){0.f, 0.f, 0.f, 0.f};

    for (int s0 = 0; s0 < TCTX; s0 += BK) {
        __syncthreads();  // A: prior tile's Kh/Kl/Vth/Vtl/Ph/Pl/Ss reads complete

        if (tid < 256) {
            // ---- waves 0-3: K direct load + LayerNorm K (R12 verbatim; r=0..63) ----
            const float* kp = qkv + (size_t)(s0 + r) * W3 + h * 192 + 64 + j * 16;
            f32x4 k0 = *(const f32x4*)(kp);
            f32x4 k1 = *(const f32x4*)(kp + 4);
            f32x4 k2 = *(const f32x4*)(kp + 8);
            f32x4 k3 = *(const f32x4*)(kp + 12);
            float s = 0.f, s2 = 0.f;
            #pragma unroll
            for (int i = 0; i < 16; ++i) {
                float x = (i < 4 ? k0[i & 3] : i < 8 ? k1[i & 3] : i < 12 ? k2[i & 3] : k3[i & 3]);
                s += x; s2 += x * x;
            }
            s  += __shfl_xor(s, 1);  s  += __shfl_xor(s, 2);
            s2 += __shfl_xor(s2, 1); s2 += __shfl_xor(s2, 2);
            float mu   = s * (1.f / 64.f);
            float var  = s2 * (1.f / 64.f) - mu * mu;
            float rsig = rsqrtf(var + 1e-6f);
            unsigned short hi[16], lo[16];
            #pragma unroll
            for (int i = 0; i < 16; ++i) {
                int c = j * 16 + i;
                float x = (i < 4 ? k0[i & 3] : i < 8 ? k1[i & 3] : i < 12 ? k2[i & 3] : k3[i & 3]);
                float y = ((x - mu) * rsig * k_gamma[c] + k_beta[c]) * scale;
                unsigned short yh = f2bf(y);
                hi[i] = yh;
                lo[i] = f2bf(y - bf2f(yh));
            }
            uint4* dh = (uint4*)(Kh + r * HSTR + j * 16);
            dh[0] = make_uint4(PK2(hi[0],hi[1]), PK2(hi[2],hi[3]), PK2(hi[4],hi[5]), PK2(hi[6],hi[7]));
            dh[1] = make_uint4(PK2(hi[8],hi[9]), PK2(hi[10],hi[11]), PK2(hi[12],hi[13]), PK2(hi[14],hi[15]));
            uint4* dl = (uint4*)(Kl + r * HSTR + j * 16);
            dl[0] = make_uint4(PK2(lo[0],lo[1]), PK2(lo[2],lo[3]), PK2(lo[4],lo[5]), PK2(lo[6],lo[7]));
            dl[1] = make_uint4(PK2(lo[8],lo[9]), PK2(lo[10],lo[11]), PK2(lo[12],lo[13]), PK2(lo[14],lo[15]));
        } else {
            // ---- waves 4-7: stage V transposed hi/lo (R12 verbatim via r2=r-64) ----
            const int r2 = r - 64;  // 0..63
            const float4* src = (const float4*)(qkv + (size_t)(s0 + r2) * W3 + h * 192 + 128 + j * 16);
            #pragma unroll
            for (int c = 0; c < 4; ++c) {
                float4 v4 = src[c];
                float vv[4] = {v4.x, v4.y, v4.z, v4.w};
                #pragma unroll
                for (int k = 0; k < 4; ++k) {
                    unsigned short vh = f2bf(vv[k]);
                    Vth[(j*16 + 4*c + k) * HSTR + r2] = vh;
                    Vtl[(j*16 + 4*c + k) * HSTR + r2] = f2bf(vv[k] - bf2f(vh));
                }
            }
        }
        __syncthreads();  // C: Kh/Kl + Vth/Vtl visible

        // ---- S = Q K^T via split MFMA, scatter C-layout -> Ss fp32 (R12 verbatim) ----
        {
            f32x4 accs[4];
            #pragma unroll
            for (int t = 0; t < 4; ++t) accs[t] = (f32x4){0.f, 0.f, 0.f, 0.f};
            #pragma unroll
            for (int s = 0; s < 2; ++s) {
                bf16x8 qh = s ? qh1 : qh0;
                bf16x8 ql = s ? ql1 : ql0;
                #pragma unroll
                for (int t = 0; t < 4; ++t) {
                    bf16x8 kh = *(const bf16x8*)(Kh + (t*16 + l15) * HSTR + s*32 + quad*8);
                    bf16x8 kl = *(const bf16x8*)(Kl + (t*16 + l15) * HSTR + s*32 + quad*8);
                    accs[t] = __builtin_amdgcn_mfma_f32_16x16x32_bf16(ql, kh, accs[t], 0, 0, 0);
                    accs[t] = __builtin_amdgcn_mfma_f32_16x16x32_bf16(qh, kl, accs[t], 0, 0, 0);
                    accs[t] = __builtin_amdgcn_mfma_f32_16x16x32_bf16(qh, kh, accs[t], 0, 0, 0);
                }
            }
            #pragma unroll
            for (int t = 0; t < 4; ++t)
                #pragma unroll
                for (int i = 0; i < 4; ++i)
                    Ss[(m0 + quad*4 + i) * LSTR + t*16 + l15] = accs[t][i];
        }
        __syncthreads();  // D: Ss visible

        // ---- softmax in (r,j) layout (R12 verbatim; rows 0..127) ----
        {
            float sv[16];
            for (int i = 0; i < 16; ++i)
                sv[i] = Ss[r * LSTR + j * 16 + i];

            float tmax = sv[0];
            for (int i = 1; i < 16; ++i) tmax = fmaxf(tmax, sv[i]);
            tmax = fmaxf(tmax, __shfl_xor(tmax, 1));
            tmax = fmaxf(tmax, __shfl_xor(tmax, 2));
            float new_m = fmaxf(m, tmax);
            float alpha = __expf(m - new_m);
            float psum = 0.f;
            unsigned short hi[16], lo[16];
            for (int i = 0; i < 16; ++i) {
                float p = __expf(sv[i] - new_m);
                psum += p;
                unsigned short ph = f2bf(p);
                hi[i] = ph;
                lo[i] = f2bf(p - bf2f(ph));
            }
            psum += __shfl_xor(psum, 1);
            psum += __shfl_xor(psum, 2);
            l = l * alpha + psum;
            m = new_m;
            uint4* dh = (uint4*)(Ph + r * HSTR + j * 16);
            dh[0] = make_uint4(PK2(hi[0],hi[1]), PK2(hi[2],hi[3]), PK2(hi[4],hi[5]), PK2(hi[6],hi[7]));
            dh[1] = make_uint4(PK2(hi[8],hi[9]), PK2(hi[10],hi[11]), PK2(hi[12],hi[13]), PK2(hi[14],hi[15]));
            uint4* dl = (uint4*)(Pl + r * HSTR + j * 16);
            dl[0] = make_uint4(PK2(lo[0],lo[1]), PK2(lo[2],lo[3]), PK2(lo[4],lo[5]), PK2(lo[6],lo[7]));
            dl[1] = make_uint4(PK2(lo[8],lo[9]), PK2(lo[10],lo[11]), PK2(lo[12],lo[13]), PK2(lo[14],lo[15]));
            if (j == 0) axs[r] = alpha;
        }
        __syncthreads();  // E: Ph/Pl + axs visible

        // ---- rescale O (C-layout rows m0+quad*4+i) ----
        {
            float af[4];
            #pragma unroll
            for (int i = 0; i < 4; ++i) af[i] = axs[m0 + quad*4 + i];
            #pragma unroll
            for (int t = 0; t < 4; ++t)
                #pragma unroll
                for (int i = 0; i < 4; ++i)
                    acco[t][i] *= af[i];
        }

        // ---- O += P V via split MFMA (R12 verbatim) ----
        #pragma unroll
        for (int s = 0; s < 2; ++s) {
            bf16x8 pa_h = *(const bf16x8*)(Ph + (m0 + l15) * HSTR + s*32 + quad*8);
            bf16x8 pa_l = *(const bf16x8*)(Pl + (m0 + l15) * HSTR + s*32 + quad*8);
            #pragma unroll
            for (int t = 0; t < 4; ++t) {
                bf16x8 vb_h = *(const bf16x8*)(Vth + (t*16 + l15) * HSTR + s*32 + quad*8);
                bf16x8 vb_l = *(const bf16x8*)(Vtl + (t*16 + l15) * HSTR + s*32 + quad*8);
                acco[t] = __builtin_amdgcn_mfma_f32_16x16x32_bf16(pa_l, vb_h, acco[t], 0, 0, 0);
                acco[t] = __builtin_amdgcn_mfma_f32_16x16x32_bf16(pa_h, vb_l, acco[t], 0, 0, 0);
                acco[t] = __builtin_amdgcn_mfma_f32_16x16x32_bf16(pa_h, vb_h, acco[t], 0, 0, 0);
            }
        }
    }

    // ---- epilogue: 1/l broadcast, normalize, C-layout store (R12 verbatim) ----
    if (j == 0) lin[r] = 1.f / l;
    __syncthreads();
    {
        float il[4];
        #pragma unroll
        for (int i = 0; i < 4; ++i) il[i] = lin[m0 + quad*4 + i];
        #pragma unroll
        for (int i = 0; i < 4; ++i) {
            const int row = q0 + m0 + quad*4 + i;
            float* op = out + (size_t)row * (HEADS * 64) + h * 64 + l15;
            #pragma unroll
            for (int t = 0; t < 4; ++t)
                op[t * 16] = acco[t][i] * il[i];
        }
    }
}

extern "C" void kernel_launch(void* const* d_in, const int* in_sizes, int n_in,
                              void* d_out, int out_size, void* d_ws, size_t ws_size,
                              hipStream_t stream) {
    const float* qkv     = (const float*)d_in[0];
    const float* q_gamma = (const float*)d_in[1];
    const float* q_beta  = (const float*)d_in[2];
    const float* k_gamma = (const float*)d_in[3];
    const float* k_beta  = (const float*)d_in[4];
    float* out = (float*)d_out;

    dim3 grid(TCTX / BQ, HEADS);
    attn_r16_kernel<<<grid, NT, 0, stream>>>(qkv, q_gamma, q_beta,
                                             k_gamma, k_beta, out);
}

// Round 10
// 510.728 us; speedup vs baseline: 2.9143x; 1.1869x over previous
//
#include <hip/hip_runtime.h>
#include <math.h>

#define TCTX 4096
#define HEADS 16
#define W3 3072
#define BQ 128   // 128 query rows per block (8 waves)
#define BK 64
#define NT 512
#define LSTR 65   // float LDS row stride (proven layout)
#define HSTR 72   // short LDS row stride (144B rows, 16B aligned)

typedef short bf16x8 __attribute__((ext_vector_type(8)));
typedef float f32x4 __attribute__((ext_vector_type(4)));

static __device__ __forceinline__ unsigned short f2bf(float x) {
    union { float f; unsigned int u; } v; v.f = x;
    unsigned int r = v.u + 0x7fffu + ((v.u >> 16) & 1u);  // RNE
    return (unsigned short)(r >> 16);
}
static __device__ __forceinline__ float bf2f(unsigned short h) {
    union { float f; unsigned int u; } v; v.u = ((unsigned int)h) << 16;
    return v.f;
}
#define PK2(a,b) ((unsigned int)(a) | ((unsigned int)(b) << 16))

// R17 = R16 (verified: passed, absmax bitwise 4.88e-4, 606us, 1 block/CU by
// LDS=144896>81920 — the session's co-residency-safe regime) with ONE
// value-identical delta: async K/V prefetch (T14). The tile-t+1 K/V global
// loads (which depend on nothing in LDS) are issued at the START of tile t's
// PV phase; the stage phase consumes registers instead of stalling on the
// load latency. Same addresses, same data, same math, same thread mapping
// => output bitwise identical to R16.
__global__ __launch_bounds__(NT, 1) void attn_r17_kernel(
    const float* __restrict__ qkv,
    const float* __restrict__ q_gamma, const float* __restrict__ q_beta,
    const float* __restrict__ k_gamma, const float* __restrict__ k_beta,
    float* __restrict__ out)
{
    __shared__ float Ss[BQ * LSTR];                              // 33280 B
    __shared__ unsigned short Qh[BQ * HSTR], Ql[BQ * HSTR];      // 36864 B
    __shared__ unsigned short Kh[BK * HSTR], Kl[BK * HSTR];      // 18432 B
    __shared__ unsigned short Vth[64 * HSTR], Vtl[64 * HSTR];    // 18432 B [ch][key]
    __shared__ unsigned short Ph[BQ * HSTR], Pl[BQ * HSTR];      // 36864 B [row][key]
    __shared__ float axs[BQ];   // per-row alpha
    __shared__ float lin[BQ];   // per-row 1/l
    // total 144896 B -> exactly 1 block/CU on gfx950 (160 KiB LDS)

    const int tid  = threadIdx.x;
    const int h    = blockIdx.y;
    const int q0   = blockIdx.x * BQ;
    const int lane = tid & 63;
    const int wv   = tid >> 6;          // 0..7
    const int l15  = lane & 15;
    const int quad = lane >> 4;
    const int m0   = wv * 16;           // 0..112
    const int r    = tid >> 2;          // 0..127
    const int j    = tid & 3;

    const float scale = 0.35355339059327373f;  // 64^(-1/4)

    // ---- LayerNorm Q: direct global->reg load (R12 order), rows 0..127 ----
    {
        const float* qp = qkv + (size_t)(q0 + r) * W3 + h * 192 + j * 16;
        f32x4 x0 = *(const f32x4*)(qp);
        f32x4 x1 = *(const f32x4*)(qp + 4);
        f32x4 x2 = *(const f32x4*)(qp + 8);
        f32x4 x3 = *(const f32x4*)(qp + 12);
        float s = 0.f, s2 = 0.f;
        #pragma unroll
        for (int i = 0; i < 16; ++i) {
            float x = (i < 4 ? x0[i & 3] : i < 8 ? x1[i & 3] : i < 12 ? x2[i & 3] : x3[i & 3]);
            s += x; s2 += x * x;
        }
        s  += __shfl_xor(s, 1);  s  += __shfl_xor(s, 2);
        s2 += __shfl_xor(s2, 1); s2 += __shfl_xor(s2, 2);
        float mu   = s * (1.f / 64.f);
        float var  = s2 * (1.f / 64.f) - mu * mu;
        float rsig = rsqrtf(var + 1e-6f);
        unsigned short hi[16], lo[16];
        #pragma unroll
        for (int i = 0; i < 16; ++i) {
            int c = j * 16 + i;
            float x = (i < 4 ? x0[i & 3] : i < 8 ? x1[i & 3] : i < 12 ? x2[i & 3] : x3[i & 3]);
            float y = ((x - mu) * rsig * q_gamma[c] + q_beta[c]) * scale;
            unsigned short yh = f2bf(y);
            hi[i] = yh;
            lo[i] = f2bf(y - bf2f(yh));
        }
        uint4* dh = (uint4*)(Qh + r * HSTR + j * 16);
        dh[0] = make_uint4(PK2(hi[0],hi[1]), PK2(hi[2],hi[3]), PK2(hi[4],hi[5]), PK2(hi[6],hi[7]));
        dh[1] = make_uint4(PK2(hi[8],hi[9]), PK2(hi[10],hi[11]), PK2(hi[12],hi[13]), PK2(hi[14],hi[15]));
        uint4* dl = (uint4*)(Ql + r * HSTR + j * 16);
        dl[0] = make_uint4(PK2(lo[0],lo[1]), PK2(lo[2],lo[3]), PK2(lo[4],lo[5]), PK2(lo[6],lo[7]));
        dl[1] = make_uint4(PK2(lo[8],lo[9]), PK2(lo[10],lo[11]), PK2(lo[12],lo[13]), PK2(lo[14],lo[15]));
    }
    __syncthreads();

    // hoist Q fragments (A[m=lane&15][k=quad*8+j]) — Qh/Ql LDS dead afterwards
    bf16x8 qh0 = *(const bf16x8*)(Qh + (m0 + l15) * HSTR +      quad * 8);
    bf16x8 qh1 = *(const bf16x8*)(Qh + (m0 + l15) * HSTR + 32 + quad * 8);
    bf16x8 ql0 = *(const bf16x8*)(Ql + (m0 + l15) * HSTR +      quad * 8);
    bf16x8 ql1 = *(const bf16x8*)(Ql + (m0 + l15) * HSTR + 32 + quad * 8);

    // softmax state per thread (r,j); O accumulator in MFMA C-layout per lane
    float m = -1e30f;
    float l = 0.f;
    f32x4 acco[4];
    #pragma unroll
    for (int t = 0; t < 4; ++t) acco[t] = (f32x4){0.f, 0.f, 0.f, 0.f};

    // ---- prefetch registers for K (waves 0-3) / V (waves 4-7), tile 0 ----
    f32x4 kq0, kq1, kq2, kq3;
    float4 vv0, vv1, vv2, vv3;
    if (tid < 256) {
        const float* kp = qkv + (size_t)(0 + r) * W3 + h * 192 + 64 + j * 16;
        kq0 = *(const f32x4*)(kp);
        kq1 = *(const f32x4*)(kp + 4);
        kq2 = *(const f32x4*)(kp + 8);
        kq3 = *(const f32x4*)(kp + 12);
    } else {
        const int r2 = r - 64;
        const float4* src = (const float4*)(qkv + (size_t)(0 + r2) * W3 + h * 192 + 128 + j * 16);
        vv0 = src[0]; vv1 = src[1]; vv2 = src[2]; vv3 = src[3];
    }

    for (int s0 = 0; s0 < TCTX; s0 += BK) {
        __syncthreads();  // A: prior tile's Kh/Kl/Vth/Vtl/Ph/Pl/Ss reads complete

        if (tid < 256) {
            // ---- waves 0-3: LayerNorm K on prefetched regs (R16 math verbatim) ----
            float s = 0.f, s2 = 0.f;
            #pragma unroll
            for (int i = 0; i < 16; ++i) {
                float x = (i < 4 ? kq0[i & 3] : i < 8 ? kq1[i & 3] : i < 12 ? kq2[i & 3] : kq3[i & 3]);
                s += x; s2 += x * x;
            }
            s  += __shfl_xor(s, 1);  s  += __shfl_xor(s, 2);
            s2 += __shfl_xor(s2, 1); s2 += __shfl_xor(s2, 2);
            float mu   = s * (1.f / 64.f);
            float var  = s2 * (1.f / 64.f) - mu * mu;
            float rsig = rsqrtf(var + 1e-6f);
            unsigned short hi[16], lo[16];
            #pragma unroll
            for (int i = 0; i < 16; ++i) {
                int c = j * 16 + i;
                float x = (i < 4 ? kq0[i & 3] : i < 8 ? kq1[i & 3] : i < 12 ? kq2[i & 3] : kq3[i & 3]);
                float y = ((x - mu) * rsig * k_gamma[c] + k_beta[c]) * scale;
                unsigned short yh = f2bf(y);
                hi[i] = yh;
                lo[i] = f2bf(y - bf2f(yh));
            }
            uint4* dh = (uint4*)(Kh + r * HSTR + j * 16);
            dh[0] = make_uint4(PK2(hi[0],hi[1]), PK2(hi[2],hi[3]), PK2(hi[4],hi[5]), PK2(hi[6],hi[7]));
            dh[1] = make_uint4(PK2(hi[8],hi[9]), PK2(hi[10],hi[11]), PK2(hi[12],hi[13]), PK2(hi[14],hi[15]));
            uint4* dl = (uint4*)(Kl + r * HSTR + j * 16);
            dl[0] = make_uint4(PK2(lo[0],lo[1]), PK2(lo[2],lo[3]), PK2(lo[4],lo[5]), PK2(lo[6],lo[7]));
            dl[1] = make_uint4(PK2(lo[8],lo[9]), PK2(lo[10],lo[11]), PK2(lo[12],lo[13]), PK2(lo[14],lo[15]));
        } else {
            // ---- waves 4-7: stage V transposed hi/lo from prefetched regs ----
            const int r2 = r - 64;  // 0..63
            #pragma unroll
            for (int c = 0; c < 4; ++c) {
                float4 v4 = (c == 0 ? vv0 : c == 1 ? vv1 : c == 2 ? vv2 : vv3);
                float vvv[4] = {v4.x, v4.y, v4.z, v4.w};
                #pragma unroll
                for (int k = 0; k < 4; ++k) {
                    unsigned short vh = f2bf(vvv[k]);
                    Vth[(j*16 + 4*c + k) * HSTR + r2] = vh;
                    Vtl[(j*16 + 4*c + k) * HSTR + r2] = f2bf(vvv[k] - bf2f(vh));
                }
            }
        }
        __syncthreads();  // C: Kh/Kl + Vth/Vtl visible

        // ---- S = Q K^T via split MFMA, scatter C-layout -> Ss fp32 (R16 verbatim) ----
        {
            f32x4 accs[4];
            #pragma unroll
            for (int t = 0; t < 4; ++t) accs[t] = (f32x4){0.f, 0.f, 0.f, 0.f};
            #pragma unroll
            for (int s = 0; s < 2; ++s) {
                bf16x8 qh = s ? qh1 : qh0;
                bf16x8 ql = s ? ql1 : ql0;
                #pragma unroll
                for (int t = 0; t < 4; ++t) {
                    bf16x8 kh = *(const bf16x8*)(Kh + (t*16 + l15) * HSTR + s*32 + quad*8);
                    bf16x8 kl = *(const bf16x8*)(Kl + (t*16 + l15) * HSTR + s*32 + quad*8);
                    accs[t] = __builtin_amdgcn_mfma_f32_16x16x32_bf16(ql, kh, accs[t], 0, 0, 0);
                    accs[t] = __builtin_amdgcn_mfma_f32_16x16x32_bf16(qh, kl, accs[t], 0, 0, 0);
                    accs[t] = __builtin_amdgcn_mfma_f32_16x16x32_bf16(qh, kh, accs[t], 0, 0, 0);
                }
            }
            #pragma unroll
            for (int t = 0; t < 4; ++t)
                #pragma unroll
                for (int i = 0; i < 4; ++i)
                    Ss[(m0 + quad*4 + i) * LSTR + t*16 + l15] = accs[t][i];
        }
        __syncthreads();  // D: Ss visible

        // ---- softmax in (r,j) layout (R16 verbatim; rows 0..127) ----
        {
            float sv[16];
            for (int i = 0; i < 16; ++i)
                sv[i] = Ss[r * LSTR + j * 16 + i];

            float tmax = sv[0];
            for (int i = 1; i < 16; ++i) tmax = fmaxf(tmax, sv[i]);
            tmax = fmaxf(tmax, __shfl_xor(tmax, 1));
            tmax = fmaxf(tmax, __shfl_xor(tmax, 2));
            float new_m = fmaxf(m, tmax);
            float alpha = __expf(m - new_m);
            float psum = 0.f;
            unsigned short hi[16], lo[16];
            for (int i = 0; i < 16; ++i) {
                float p = __expf(sv[i] - new_m);
                psum += p;
                unsigned short ph = f2bf(p);
                hi[i] = ph;
                lo[i] = f2bf(p - bf2f(ph));
            }
            psum += __shfl_xor(psum, 1);
            psum += __shfl_xor(psum, 2);
            l = l * alpha + psum;
            m = new_m;
            uint4* dh = (uint4*)(Ph + r * HSTR + j * 16);
            dh[0] = make_uint4(PK2(hi[0],hi[1]), PK2(hi[2],hi[3]), PK2(hi[4],hi[5]), PK2(hi[6],hi[7]));
            dh[1] = make_uint4(PK2(hi[8],hi[9]), PK2(hi[10],hi[11]), PK2(hi[12],hi[13]), PK2(hi[14],hi[15]));
            uint4* dl = (uint4*)(Pl + r * HSTR + j * 16);
            dl[0] = make_uint4(PK2(lo[0],lo[1]), PK2(lo[2],lo[3]), PK2(lo[4],lo[5]), PK2(lo[6],lo[7]));
            dl[1] = make_uint4(PK2(lo[8],lo[9]), PK2(lo[10],lo[11]), PK2(lo[12],lo[13]), PK2(lo[14],lo[15]));
            if (j == 0) axs[r] = alpha;
        }
        __syncthreads();  // E: Ph/Pl + axs visible

        // ---- rescale O (C-layout rows m0+quad*4+i) ----
        {
            float af[4];
            #pragma unroll
            for (int i = 0; i < 4; ++i) af[i] = axs[m0 + quad*4 + i];
            #pragma unroll
            for (int t = 0; t < 4; ++t)
                #pragma unroll
                for (int i = 0; i < 4; ++i)
                    acco[t][i] *= af[i];
        }

        // ---- NEW: issue next tile's K/V global loads (in flight across PV) ----
        if (s0 + BK < TCTX) {
            const int sn = s0 + BK;
            if (tid < 256) {
                const float* kp = qkv + (size_t)(sn + r) * W3 + h * 192 + 64 + j * 16;
                kq0 = *(const f32x4*)(kp);
                kq1 = *(const f32x4*)(kp + 4);
                kq2 = *(const f32x4*)(kp + 8);
                kq3 = *(const f32x4*)(kp + 12);
            } else {
                const int r2 = r - 64;
                const float4* src = (const float4*)(qkv + (size_t)(sn + r2) * W3 + h * 192 + 128 + j * 16);
                vv0 = src[0]; vv1 = src[1]; vv2 = src[2]; vv3 = src[3];
            }
        }

        // ---- O += P V via split MFMA (R16 verbatim) ----
        #pragma unroll
        for (int s = 0; s < 2; ++s) {
            bf16x8 pa_h = *(const bf16x8*)(Ph + (m0 + l15) * HSTR + s*32 + quad*8);
            bf16x8 pa_l = *(const bf16x8*)(Pl + (m0 + l15) * HSTR + s*32 + quad*8);
            #pragma unroll
            for (int t = 0; t < 4; ++t) {
                bf16x8 vb_h = *(const bf16x8*)(Vth + (t*16 + l15) * HSTR + s*32 + quad*8);
                bf16x8 vb_l = *(const bf16x8*)(Vtl + (t*16 + l15) * HSTR + s*32 + quad*8);
                acco[t] = __builtin_amdgcn_mfma_f32_16x16x32_bf16(pa_l, vb_h, acco[t], 0, 0, 0);
                acco[t] = __builtin_amdgcn_mfma_f32_16x16x32_bf16(pa_h, vb_l, acco[t], 0, 0, 0);
                acco[t] = __builtin_amdgcn_mfma_f32_16x16x32_bf16(pa_h, vb_h, acco[t], 0, 0, 0);
            }
        }
    }

    // ---- epilogue: 1/l broadcast, normalize, C-layout store (R16 verbatim) ----
    if (j == 0) lin[r] = 1.f / l;
    __syncthreads();
    {
        float il[4];
        #pragma unroll
        for (int i = 0; i < 4; ++i) il[i] = lin[m0 + quad*4 + i];
        #pragma unroll
        for (int i = 0; i < 4; ++i) {
            const int row = q0 + m0 + quad*4 + i;
            float* op = out + (size_t)row * (HEADS * 64) + h * 64 + l15;
            #pragma unroll
            for (int t = 0; t < 4; ++t)
                op[t * 16] = acco[t][i] * il[i];
        }
    }
}

extern "C" void kernel_launch(void* const* d_in, const int* in_sizes, int n_in,
                              void* d_out, int out_size, void* d_ws, size_t ws_size,
                              hipStream_t stream) {
    const float* qkv     = (const float*)d_in[0];
    const float* q_gamma = (const float*)d_in[1];
    const float* q_beta  = (const float*)d_in[2];
    const float* k_gamma = (const float*)d_in[3];
    const float* k_beta  = (const float*)d_in[4];
    float* out = (float*)d_out;

    dim3 grid(TCTX / BQ, HEADS);
    attn_r17_kernel<<<grid, NT, 0, stream>>>(qkv, q_gamma, q_beta,
                                             k_gamma, k_beta, out);
}